// Round 2
// baseline (2008.622 us; speedup 1.0000x reference)
//
#include <hip/hip_runtime.h>

#define HW 4096
#define NE 1024
#define LOSS_OFF 16777216
#define IDX_OFF  16777218
#define KP  264
#define KPB 528           // bytes per LDS tile row
#define MARGIN 0.35f

typedef __attribute__((ext_vector_type(8))) short short8v;
typedef __attribute__((ext_vector_type(4))) float float4v;

// ws layout (bytes): [0] int flag_count; [64..) int flaglist[65536];
// [262208..) float cnorm[1024]; [266304..) ushort cbh[1024*256]; [790592..) float part[4096]
#define WS_LIST_OFF   64
#define WS_CNORM_OFF  262208
#define WS_CBH_OFF    266304
#define WS_PART_OFF   790592

__device__ __forceinline__ unsigned short bf16rne(float f) {
    unsigned u = __float_as_uint(f);
    u += 0x7FFFu + ((u >> 16) & 1u);
    return (unsigned short)(u >> 16);
}

// ---------------- k0: codebook half-norms + bf16 conversion + counter zero ----------------
__global__ __launch_bounds__(256) void k0_prep(const float* __restrict__ cb,
                                               float* __restrict__ cnorm,
                                               unsigned short* __restrict__ cbh,
                                               int* __restrict__ flagcnt) {
    int e = blockIdx.x * 256 + threadIdx.x;   // grid 4 x 256 = 1024
    if (e == 0) *flagcnt = 0;
    const float4* row = (const float4*)(cb + (size_t)e * 256);
    unsigned short* dst = cbh + (size_t)e * 256;
    float s = 0.f;
#pragma unroll 8
    for (int i = 0; i < 64; ++i) {
        float4 v = row[i];
        s += v.x * v.x + v.y * v.y + v.z * v.z + v.w * v.w;
        unsigned p0 = (unsigned)bf16rne(v.x) | ((unsigned)bf16rne(v.y) << 16);
        unsigned p1 = (unsigned)bf16rne(v.z) | ((unsigned)bf16rne(v.w) << 16);
        *(uint2*)(dst + i * 4) = make_uint2(p0, p1);
    }
    cnorm[e] = 0.5f * s;
}

// ---------------- k1: MFMA approx distance + argmin(best1,best2) + flagging ----------------
__global__ __launch_bounds__(256, 2) void k1_mfma(const float* __restrict__ z,
                                                  const unsigned short* __restrict__ cbh,
                                                  const float* __restrict__ cnorm,
                                                  float* __restrict__ out_idx,
                                                  int* __restrict__ flagcnt,
                                                  int* __restrict__ flaglist) {
    __shared__ __align__(16) char smem[69632];
    char* zt = smem;                         // [64][KP] bf16 (aliases cb buf0; dead after A-read)
    char* cbbuf0 = smem;                     // [64][KP] bf16
    char* cbbuf1 = smem + 33792;
    float* cand1 = (float*)(smem + 67584);   // [64][2]
    int*   candi = (int*)  (smem + 68096);
    float* cand2 = (float*)(smem + 68608);

    const int tid = threadIdx.x;
    const int n0 = blockIdx.x * 64;
    const int hw0 = n0 & 4095;
    const float* zb = z + (size_t)(n0 >> 12) * (256 * HW);

    // ---- stage z tile transposed: [row][k] bf16 ----
    {
        const int row = tid & 63, kg8 = tid >> 6;
#pragma unroll
        for (int it = 0; it < 8; ++it) {
            int kb = (kg8 + it * 4) * 8;
            float v[8];
#pragma unroll
            for (int q = 0; q < 8; ++q) v[q] = zb[(size_t)(kb + q) * HW + hw0 + row];
            unsigned pk[4];
#pragma unroll
            for (int q = 0; q < 4; ++q)
                pk[q] = (unsigned)bf16rne(v[2*q]) | ((unsigned)bf16rne(v[2*q+1]) << 16);
            *(int4*)(zt + row * KPB + kb * 2) = make_int4(pk[0], pk[1], pk[2], pk[3]);
        }
    }
    __syncthreads();

    const int wid = tid >> 6, l = tid & 63;
    const int wy = wid >> 1, wx = wid & 1;
    const int lr = l & 15, lg = l >> 4;

    // ---- cache A-frags (this wave's 32 rows, full K) in registers ----
    short8v A[2][8];
#pragma unroll
    for (int mi = 0; mi < 2; ++mi)
#pragma unroll
        for (int ks = 0; ks < 8; ++ks)
            A[mi][ks] = *(const short8v*)(zt + (32*wy + 16*mi + lr) * KPB + (32*ks + 8*lg) * 2);
    __syncthreads();   // zt dead; cb buffers may now overwrite it

    // ---- stage codebook chunk 0 (64 entries x 256 k, bf16) ----
    const int se = tid >> 2;        // 0..63 entry
    const int sk0 = tid & 3;
#pragma unroll
    for (int it = 0; it < 8; ++it) {
        int kg = sk0 + it * 4;      // 0..31 (16B chunks)
        int4 v = *(const int4*)(cbh + (size_t)se * 256 + kg * 8);
        *(int4*)(cbbuf0 + se * KPB + kg * 16) = v;
    }
    __syncthreads();

    float b1[8], b2[8]; int bi[8];
#pragma unroll
    for (int i = 0; i < 8; ++i) { b1[i] = 1e30f; b2[i] = 1e30f; bi[i] = 0; }

    int buf = 0;
    for (int e0c = 0; e0c < 16; ++e0c) {
        // T14: issue next chunk's global loads early (into regs)
        int4 pf[8];
        if (e0c < 15) {
            const unsigned short* src = cbh + (size_t)(e0c + 1) * 64 * 256;
#pragma unroll
            for (int it = 0; it < 8; ++it) {
                int kg = sk0 + it * 4;
                pf[it] = *(const int4*)(src + (size_t)se * 256 + kg * 8);
            }
        }

        const char* cbp = buf ? cbbuf1 : cbbuf0;
        float4v acc00 = {0.f,0.f,0.f,0.f}, acc01 = acc00, acc10 = acc00, acc11 = acc00;
#pragma unroll
        for (int ks = 0; ks < 8; ++ks) {
            short8v B0 = *(const short8v*)(cbp + (32*wx + lr) * KPB + (32*ks + 8*lg) * 2);
            short8v B1 = *(const short8v*)(cbp + (32*wx + 16 + lr) * KPB + (32*ks + 8*lg) * 2);
            acc00 = __builtin_amdgcn_mfma_f32_16x16x32_bf16(A[0][ks], B0, acc00, 0, 0, 0);
            acc01 = __builtin_amdgcn_mfma_f32_16x16x32_bf16(A[0][ks], B1, acc01, 0, 0, 0);
            acc10 = __builtin_amdgcn_mfma_f32_16x16x32_bf16(A[1][ks], B0, acc10, 0, 0, 0);
            acc11 = __builtin_amdgcn_mfma_f32_16x16x32_bf16(A[1][ks], B1, acc11, 0, 0, 0);
        }

        // fold into best1/best2 (entries ascending -> strict < keeps smallest index)
        float cn0 = cnorm[e0c * 64 + 32 * wx + lr];
        float cn1 = cnorm[e0c * 64 + 32 * wx + 16 + lr];
        int e0v = e0c * 64 + 32 * wx + lr;
#pragma unroll
        for (int mi = 0; mi < 2; ++mi) {
            const float4v a0 = mi ? acc10 : acc00;
            const float4v a1 = mi ? acc11 : acc01;
#pragma unroll
            for (int r = 0; r < 4; ++r) {
                int slot = mi * 4 + r;
                float s0 = cn0 - a0[r];
                if (s0 < b1[slot]) { b2[slot] = b1[slot]; b1[slot] = s0; bi[slot] = e0v; }
                else if (s0 < b2[slot]) b2[slot] = s0;
                float s1 = cn1 - a1[r];
                if (s1 < b1[slot]) { b2[slot] = b1[slot]; b1[slot] = s1; bi[slot] = e0v + 16; }
                else if (s1 < b2[slot]) b2[slot] = s1;
            }
        }

        if (e0c < 15) {
            char* dst = buf ? cbbuf0 : cbbuf1;
#pragma unroll
            for (int it = 0; it < 8; ++it) {
                int kg = sk0 + it * 4;
                *(int4*)(dst + se * KPB + kg * 16) = pf[it];
            }
        }
        __syncthreads();
        buf ^= 1;
    }

    // ---- cross-lane argmin over the 16-lane entry dimension ----
#pragma unroll
    for (int m = 1; m <= 8; m <<= 1) {
#pragma unroll
        for (int s = 0; s < 8; ++s) {
            float o1 = __shfl_xor(b1[s], m, 64);
            float o2 = __shfl_xor(b2[s], m, 64);
            int   oi = __shfl_xor(bi[s], m, 64);
            float m2 = fminf(fmaxf(b1[s], o1), fminf(b2[s], o2));
            if (o1 < b1[s] || (o1 == b1[s] && oi < bi[s])) { b1[s] = o1; bi[s] = oi; }
            b2[s] = m2;
        }
    }
    if (lr == 0) {
#pragma unroll
        for (int mi = 0; mi < 2; ++mi)
#pragma unroll
            for (int r = 0; r < 4; ++r) {
                int row = 32 * wy + 16 * mi + 4 * lg + r;
                cand1[row * 2 + wx] = b1[mi * 4 + r];
                cand2[row * 2 + wx] = b2[mi * 4 + r];
                candi[row * 2 + wx] = bi[mi * 4 + r];
            }
    }
    __syncthreads();
    if (tid < 64) {
        float s1a = cand1[tid * 2], s1b = cand1[tid * 2 + 1];
        int   ia = candi[tid * 2],  ib = candi[tid * 2 + 1];
        float s2 = fminf(fminf(cand2[tid * 2], cand2[tid * 2 + 1]), fmaxf(s1a, s1b));
        float s1; int iw;
        if (s1b < s1a || (s1b == s1a && ib < ia)) { s1 = s1b; iw = ib; }
        else { s1 = s1a; iw = ia; }
        out_idx[n0 + tid] = (float)iw;
        if (s2 - s1 < MARGIN) {
            int p = atomicAdd(flagcnt, 1);
            flaglist[p] = n0 + tid;
        }
    }
}

// ---------------- k1b: exact fp32 re-argmin for flagged rows (batched 32/block) ----------------
__global__ __launch_bounds__(256) void k1b_refine(const float* __restrict__ z,
                                                  const float* __restrict__ cb,
                                                  const float* __restrict__ cnorm,
                                                  const int* __restrict__ flagcnt,
                                                  const int* __restrict__ flaglist,
                                                  float* __restrict__ out_idx) {
    __shared__ float zr[32][256];
    __shared__ int rows[32];
    __shared__ float red_s[32][8];
    __shared__ int   red_i[32][8];
    const int tid = threadIdx.x;
    const int count = *flagcnt;
    for (int base = blockIdx.x * 32; base < count; base += gridDim.x * 32) {
        int nr = min(32, count - base);
        if (tid < 32) rows[tid] = (tid < nr) ? flaglist[base + tid] : 0;
        __syncthreads();
        for (int rr = 0; rr < nr; ++rr) {
            int n = rows[rr];
            zr[rr][tid] = z[((size_t)(n >> 12) * 256 + tid) * HW + (n & 4095)];
        }
        __syncthreads();
        int r = tid >> 3, ec = tid & 7;
        if (r < nr) {
            const float* zrow = zr[r];
            float best = 1e30f; int bidx = 0;
            for (int e = ec * 128; e < ec * 128 + 128; ++e) {
                const float4* cv = (const float4*)(cb + (size_t)e * 256);
                float d0 = 0.f, d1 = 0.f, d2 = 0.f, d3 = 0.f;
#pragma unroll 16
                for (int q = 0; q < 64; ++q) {
                    float4 c = cv[q];
                    float4 zv = *(const float4*)(zrow + q * 4);
                    d0 = fmaf(zv.x, c.x, d0); d1 = fmaf(zv.y, c.y, d1);
                    d2 = fmaf(zv.z, c.z, d2); d3 = fmaf(zv.w, c.w, d3);
                }
                float s = cnorm[e] - ((d0 + d1) + (d2 + d3));
                if (s < best) { best = s; bidx = e; }
            }
            red_s[r][ec] = best; red_i[r][ec] = bidx;
        }
        __syncthreads();
        if (tid < nr) {
            float best = red_s[tid][0]; int bidx = red_i[tid][0];
#pragma unroll
            for (int q = 1; q < 8; ++q)
                if (red_s[tid][q] < best) { best = red_s[tid][q]; bidx = red_i[tid][q]; }
            out_idx[rows[tid]] = (float)bidx;
        }
        __syncthreads();
    }
}

// ---------------- k2: gather z_q + fused loss partials ----------------
__global__ __launch_bounds__(256) void k2_scatter(const float* __restrict__ z,
                                                  const float* __restrict__ cb,
                                                  const float* __restrict__ idxf,
                                                  float* __restrict__ zq,
                                                  float* __restrict__ part) {
    __shared__ float ls[4];
    size_t base = (size_t)blockIdx.x * 256 + threadIdx.x;   // grid 4096
    float lsum = 0.f;
#pragma unroll
    for (int it = 0; it < 16; ++it) {
        size_t flat = base + (size_t)it * 1048576;
        int c = (int)((flat >> 12) & 255);
        int n = (int)(((flat >> 20) << 12) | (flat & 4095));
        int e = (int)idxf[n];
        float q = cb[e * 256 + c];
        zq[flat] = q;
        float d = q - z[flat];
        lsum += d * d;
    }
#pragma unroll
    for (int m = 32; m >= 1; m >>= 1) lsum += __shfl_down(lsum, m, 64);
    int lane = threadIdx.x & 63, w = threadIdx.x >> 6;
    if (lane == 0) ls[w] = lsum;
    __syncthreads();
    if (threadIdx.x == 0) part[blockIdx.x] = ls[0] + ls[1] + ls[2] + ls[3];
}

// ---------------- k3: final loss reduce + constants ----------------
__global__ __launch_bounds__(256) void k3_final(const float* __restrict__ part,
                                                float* __restrict__ dout) {
    __shared__ float ls[4];
    float s = 0.f;
#pragma unroll
    for (int it = 0; it < 16; ++it) s += part[threadIdx.x + it * 256];
#pragma unroll
    for (int m = 32; m >= 1; m >>= 1) s += __shfl_down(s, m, 64);
    int lane = threadIdx.x & 63, w = threadIdx.x >> 6;
    if (lane == 0) ls[w] = s;
    __syncthreads();
    if (threadIdx.x == 0) {
        float total = ls[0] + ls[1] + ls[2] + ls[3];
        dout[LOSS_OFF]     = total / 16777216.0f;
        dout[LOSS_OFF + 1] = 0.0f;
    }
}

extern "C" void kernel_launch(void* const* d_in, const int* in_sizes, int n_in,
                              void* d_out, int out_size, void* d_ws, size_t ws_size,
                              hipStream_t stream) {
    const float* z  = (const float*)d_in[0];
    const float* cb = (const float*)d_in[1];
    float* out = (float*)d_out;
    char* ws = (char*)d_ws;

    int*            flagcnt  = (int*)ws;
    int*            flaglist = (int*)(ws + WS_LIST_OFF);
    float*          cnorm    = (float*)(ws + WS_CNORM_OFF);
    unsigned short* cbh      = (unsigned short*)(ws + WS_CBH_OFF);
    float*          part     = (float*)(ws + WS_PART_OFF);

    hipLaunchKernelGGL(k0_prep,   dim3(4),    dim3(256), 0, stream, cb, cnorm, cbh, flagcnt);
    hipLaunchKernelGGL(k1_mfma,   dim3(1024), dim3(256), 0, stream,
                       z, cbh, cnorm, out + IDX_OFF, flagcnt, flaglist);
    hipLaunchKernelGGL(k1b_refine, dim3(128), dim3(256), 0, stream,
                       z, cb, cnorm, flagcnt, flaglist, out + IDX_OFF);
    hipLaunchKernelGGL(k2_scatter, dim3(4096), dim3(256), 0, stream,
                       z, cb, out + IDX_OFF, out, part);
    hipLaunchKernelGGL(k3_final,  dim3(1),    dim3(256), 0, stream, part, out);
}

// Round 3
// 699.348 us; speedup vs baseline: 2.8721x; 2.8721x over previous
//
#include <hip/hip_runtime.h>

#define HW 4096
#define NE 1024
#define LOSS_OFF 16777216
#define IDX_OFF  16777218
#define KP  264
#define KPB 528           // bytes per LDS tile row
#define MARGIN 0.35f

typedef __attribute__((ext_vector_type(8))) short short8v;
typedef __attribute__((ext_vector_type(4))) float float4v;

// ws layout (bytes): [0] int flag_count; [64..) int flaglist[65536];
// [262208..) float cnorm[1024]; [266304..) ushort cbh[1024*256]; [790592..) float part[4096]
#define WS_LIST_OFF   64
#define WS_CNORM_OFF  262208
#define WS_CBH_OFF    266304
#define WS_PART_OFF   790592

__device__ __forceinline__ unsigned short bf16rne(float f) {
    unsigned u = __float_as_uint(f);
    u += 0x7FFFu + ((u >> 16) & 1u);
    return (unsigned short)(u >> 16);
}

// ---------------- k0: codebook half-norms + bf16 conversion + counter zero ----------------
__global__ __launch_bounds__(256) void k0_prep(const float* __restrict__ cb,
                                               float* __restrict__ cnorm,
                                               unsigned short* __restrict__ cbh,
                                               int* __restrict__ flagcnt) {
    int e = blockIdx.x * 256 + threadIdx.x;   // grid 4 x 256 = 1024
    if (e == 0) *flagcnt = 0;
    const float4* row = (const float4*)(cb + (size_t)e * 256);
    unsigned short* dst = cbh + (size_t)e * 256;
    float s = 0.f;
#pragma unroll 8
    for (int i = 0; i < 64; ++i) {
        float4 v = row[i];
        s += v.x * v.x + v.y * v.y + v.z * v.z + v.w * v.w;
        unsigned p0 = (unsigned)bf16rne(v.x) | ((unsigned)bf16rne(v.y) << 16);
        unsigned p1 = (unsigned)bf16rne(v.z) | ((unsigned)bf16rne(v.w) << 16);
        *(uint2*)(dst + i * 4) = make_uint2(p0, p1);
    }
    cnorm[e] = 0.5f * s;
}

// ---------------- k1: MFMA approx distance + argmin(best1,best2) + flagging ----------------
__global__ __launch_bounds__(256, 2) void k1_mfma(const float* __restrict__ z,
                                                  const unsigned short* __restrict__ cbh,
                                                  const float* __restrict__ cnorm,
                                                  float* __restrict__ out_idx,
                                                  int* __restrict__ flagcnt,
                                                  int* __restrict__ flaglist) {
    __shared__ __align__(16) char smem[69632];
    char* zt = smem;                         // [64][KP] bf16 (aliases cb buf0; dead after A-read)
    char* cbbuf0 = smem;                     // [64][KP] bf16
    char* cbbuf1 = smem + 33792;
    float* cand1 = (float*)(smem + 67584);   // [64][2]
    int*   candi = (int*)  (smem + 68096);
    float* cand2 = (float*)(smem + 68608);

    const int tid = threadIdx.x;
    const int n0 = blockIdx.x * 64;
    const int hw0 = n0 & 4095;
    const float* zb = z + (size_t)(n0 >> 12) * (256 * HW);

    // ---- stage z tile transposed: [row][k] bf16 ----
    {
        const int row = tid & 63, kg8 = tid >> 6;
#pragma unroll
        for (int it = 0; it < 8; ++it) {
            int kb = (kg8 + it * 4) * 8;
            float v[8];
#pragma unroll
            for (int q = 0; q < 8; ++q) v[q] = zb[(size_t)(kb + q) * HW + hw0 + row];
            unsigned pk[4];
#pragma unroll
            for (int q = 0; q < 4; ++q)
                pk[q] = (unsigned)bf16rne(v[2*q]) | ((unsigned)bf16rne(v[2*q+1]) << 16);
            *(int4*)(zt + row * KPB + kb * 2) = make_int4(pk[0], pk[1], pk[2], pk[3]);
        }
    }
    __syncthreads();

    const int wid = tid >> 6, l = tid & 63;
    const int wy = wid >> 1, wx = wid & 1;
    const int lr = l & 15, lg = l >> 4;

    // ---- cache A-frags (this wave's 32 rows, full K) in registers ----
    short8v A[2][8];
#pragma unroll
    for (int mi = 0; mi < 2; ++mi)
#pragma unroll
        for (int ks = 0; ks < 8; ++ks)
            A[mi][ks] = *(const short8v*)(zt + (32*wy + 16*mi + lr) * KPB + (32*ks + 8*lg) * 2);
    __syncthreads();   // zt dead; cb buffers may now overwrite it

    // ---- stage codebook chunk 0 (64 entries x 256 k, bf16) ----
    const int se = tid >> 2;        // 0..63 entry
    const int sk0 = tid & 3;
#pragma unroll
    for (int it = 0; it < 8; ++it) {
        int kg = sk0 + it * 4;      // 0..31 (16B chunks)
        int4 v = *(const int4*)(cbh + (size_t)se * 256 + kg * 8);
        *(int4*)(cbbuf0 + se * KPB + kg * 16) = v;
    }
    __syncthreads();

    float b1[8], b2[8]; int bi[8];
#pragma unroll
    for (int i = 0; i < 8; ++i) { b1[i] = 1e30f; b2[i] = 1e30f; bi[i] = 0; }

    int buf = 0;
    for (int e0c = 0; e0c < 16; ++e0c) {
        // T14: issue next chunk's global loads early (into regs)
        int4 pf[8];
        if (e0c < 15) {
            const unsigned short* src = cbh + (size_t)(e0c + 1) * 64 * 256;
#pragma unroll
            for (int it = 0; it < 8; ++it) {
                int kg = sk0 + it * 4;
                pf[it] = *(const int4*)(src + (size_t)se * 256 + kg * 8);
            }
        }

        const char* cbp = buf ? cbbuf1 : cbbuf0;
        float4v acc00 = {0.f,0.f,0.f,0.f}, acc01 = acc00, acc10 = acc00, acc11 = acc00;
#pragma unroll
        for (int ks = 0; ks < 8; ++ks) {
            short8v B0 = *(const short8v*)(cbp + (32*wx + lr) * KPB + (32*ks + 8*lg) * 2);
            short8v B1 = *(const short8v*)(cbp + (32*wx + 16 + lr) * KPB + (32*ks + 8*lg) * 2);
            acc00 = __builtin_amdgcn_mfma_f32_16x16x32_bf16(A[0][ks], B0, acc00, 0, 0, 0);
            acc01 = __builtin_amdgcn_mfma_f32_16x16x32_bf16(A[0][ks], B1, acc01, 0, 0, 0);
            acc10 = __builtin_amdgcn_mfma_f32_16x16x32_bf16(A[1][ks], B0, acc10, 0, 0, 0);
            acc11 = __builtin_amdgcn_mfma_f32_16x16x32_bf16(A[1][ks], B1, acc11, 0, 0, 0);
        }

        // fold into best1/best2 (entries ascending -> strict < keeps smallest index)
        float cn0 = cnorm[e0c * 64 + 32 * wx + lr];
        float cn1 = cnorm[e0c * 64 + 32 * wx + 16 + lr];
        int e0v = e0c * 64 + 32 * wx + lr;
#pragma unroll
        for (int mi = 0; mi < 2; ++mi) {
            const float4v a0 = mi ? acc10 : acc00;
            const float4v a1 = mi ? acc11 : acc01;
#pragma unroll
            for (int r = 0; r < 4; ++r) {
                int slot = mi * 4 + r;
                float s0 = cn0 - a0[r];
                if (s0 < b1[slot]) { b2[slot] = b1[slot]; b1[slot] = s0; bi[slot] = e0v; }
                else if (s0 < b2[slot]) b2[slot] = s0;
                float s1 = cn1 - a1[r];
                if (s1 < b1[slot]) { b2[slot] = b1[slot]; b1[slot] = s1; bi[slot] = e0v + 16; }
                else if (s1 < b2[slot]) b2[slot] = s1;
            }
        }

        if (e0c < 15) {
            char* dst = buf ? cbbuf0 : cbbuf1;
#pragma unroll
            for (int it = 0; it < 8; ++it) {
                int kg = sk0 + it * 4;
                *(int4*)(dst + se * KPB + kg * 16) = pf[it];
            }
        }
        __syncthreads();
        buf ^= 1;
    }

    // ---- cross-lane argmin over the 16-lane entry dimension ----
#pragma unroll
    for (int m = 1; m <= 8; m <<= 1) {
#pragma unroll
        for (int s = 0; s < 8; ++s) {
            float o1 = __shfl_xor(b1[s], m, 64);
            float o2 = __shfl_xor(b2[s], m, 64);
            int   oi = __shfl_xor(bi[s], m, 64);
            float m2 = fminf(fmaxf(b1[s], o1), fminf(b2[s], o2));
            if (o1 < b1[s] || (o1 == b1[s] && oi < bi[s])) { b1[s] = o1; bi[s] = oi; }
            b2[s] = m2;
        }
    }
    if (lr == 0) {
#pragma unroll
        for (int mi = 0; mi < 2; ++mi)
#pragma unroll
            for (int r = 0; r < 4; ++r) {
                int row = 32 * wy + 16 * mi + 4 * lg + r;
                cand1[row * 2 + wx] = b1[mi * 4 + r];
                cand2[row * 2 + wx] = b2[mi * 4 + r];
                candi[row * 2 + wx] = bi[mi * 4 + r];
            }
    }
    __syncthreads();
    if (tid < 64) {
        float s1a = cand1[tid * 2], s1b = cand1[tid * 2 + 1];
        int   ia = candi[tid * 2],  ib = candi[tid * 2 + 1];
        float s2 = fminf(fminf(cand2[tid * 2], cand2[tid * 2 + 1]), fmaxf(s1a, s1b));
        float s1; int iw;
        if (s1b < s1a || (s1b == s1a && ib < ia)) { s1 = s1b; iw = ib; }
        else { s1 = s1a; iw = ia; }
        out_idx[n0 + tid] = (float)iw;
        if (s2 - s1 < MARGIN) {
            int p = atomicAdd(flagcnt, 1);
            flaglist[p] = n0 + tid;
        }
    }
}

// ---------------- k1b: exact fp32 re-argmin, ONE flagged row per block ----------------
// zr reads are wave-broadcast (same address all lanes) -> zero bank conflicts.
// Each thread owns entries {tid, tid+256, tid+512, tid+768} (ascending -> tie-break ok).
__global__ __launch_bounds__(256) void k1b_refine(const float* __restrict__ z,
                                                  const float* __restrict__ cb,
                                                  const float* __restrict__ cnorm,
                                                  const int* __restrict__ flagcnt,
                                                  const int* __restrict__ flaglist,
                                                  float* __restrict__ out_idx) {
    __shared__ float zr[256];
    __shared__ float wbest[4];
    __shared__ int   widx[4];
    const int tid = threadIdx.x;
    const int count = *flagcnt;
    for (int fi = blockIdx.x; fi < count; fi += gridDim.x) {
        const int n = flaglist[fi];
        __syncthreads();   // protect zr/wbest from previous iteration
        zr[tid] = z[((size_t)(n >> 12) * 256 + tid) * HW + (n & 4095)];
        __syncthreads();
        float best = 1e30f; int bidx = 0;
#pragma unroll
        for (int p = 0; p < 4; ++p) {
            const int e = p * 256 + tid;
            const float4* cv = (const float4*)(cb + (size_t)e * 256);
            float d0 = 0.f, d1 = 0.f, d2 = 0.f, d3 = 0.f;
#pragma unroll 16
            for (int q = 0; q < 64; ++q) {
                float4 c = cv[q];
                float4 zv = *(const float4*)(zr + q * 4);   // broadcast
                d0 = fmaf(zv.x, c.x, d0); d1 = fmaf(zv.y, c.y, d1);
                d2 = fmaf(zv.z, c.z, d2); d3 = fmaf(zv.w, c.w, d3);
            }
            float s = cnorm[e] - ((d0 + d1) + (d2 + d3));
            if (s < best) { best = s; bidx = e; }
        }
#pragma unroll
        for (int m = 1; m <= 32; m <<= 1) {
            float ob = __shfl_xor(best, m, 64);
            int   oi = __shfl_xor(bidx, m, 64);
            if (ob < best || (ob == best && oi < bidx)) { best = ob; bidx = oi; }
        }
        const int lane = tid & 63, w = tid >> 6;
        if (lane == 0) { wbest[w] = best; widx[w] = bidx; }
        __syncthreads();
        if (tid == 0) {
            float bb = wbest[0]; int ii = widx[0];
#pragma unroll
            for (int q = 1; q < 4; ++q)
                if (wbest[q] < bb || (wbest[q] == bb && widx[q] < ii)) { bb = wbest[q]; ii = widx[q]; }
            out_idx[n] = (float)ii;
        }
    }
}

// ---------------- k2: gather z_q + fused loss partials ----------------
__global__ __launch_bounds__(256) void k2_scatter(const float* __restrict__ z,
                                                  const float* __restrict__ cb,
                                                  const float* __restrict__ idxf,
                                                  float* __restrict__ zq,
                                                  float* __restrict__ part) {
    __shared__ float ls[4];
    size_t base = (size_t)blockIdx.x * 256 + threadIdx.x;   // grid 4096
    float lsum = 0.f;
#pragma unroll
    for (int it = 0; it < 16; ++it) {
        size_t flat = base + (size_t)it * 1048576;
        int c = (int)((flat >> 12) & 255);
        int n = (int)(((flat >> 20) << 12) | (flat & 4095));
        int e = (int)idxf[n];
        float q = cb[e * 256 + c];
        zq[flat] = q;
        float d = q - z[flat];
        lsum += d * d;
    }
#pragma unroll
    for (int m = 32; m >= 1; m >>= 1) lsum += __shfl_down(lsum, m, 64);
    int lane = threadIdx.x & 63, w = threadIdx.x >> 6;
    if (lane == 0) ls[w] = lsum;
    __syncthreads();
    if (threadIdx.x == 0) part[blockIdx.x] = ls[0] + ls[1] + ls[2] + ls[3];
}

// ---------------- k3: final loss reduce + constants ----------------
__global__ __launch_bounds__(256) void k3_final(const float* __restrict__ part,
                                                float* __restrict__ dout) {
    __shared__ float ls[4];
    float s = 0.f;
#pragma unroll
    for (int it = 0; it < 16; ++it) s += part[threadIdx.x + it * 256];
#pragma unroll
    for (int m = 32; m >= 1; m >>= 1) s += __shfl_down(s, m, 64);
    int lane = threadIdx.x & 63, w = threadIdx.x >> 6;
    if (lane == 0) ls[w] = s;
    __syncthreads();
    if (threadIdx.x == 0) {
        float total = ls[0] + ls[1] + ls[2] + ls[3];
        dout[LOSS_OFF]     = total / 16777216.0f;
        dout[LOSS_OFF + 1] = 0.0f;
    }
}

extern "C" void kernel_launch(void* const* d_in, const int* in_sizes, int n_in,
                              void* d_out, int out_size, void* d_ws, size_t ws_size,
                              hipStream_t stream) {
    const float* z  = (const float*)d_in[0];
    const float* cb = (const float*)d_in[1];
    float* out = (float*)d_out;
    char* ws = (char*)d_ws;

    int*            flagcnt  = (int*)ws;
    int*            flaglist = (int*)(ws + WS_LIST_OFF);
    float*          cnorm    = (float*)(ws + WS_CNORM_OFF);
    unsigned short* cbh      = (unsigned short*)(ws + WS_CBH_OFF);
    float*          part     = (float*)(ws + WS_PART_OFF);

    hipLaunchKernelGGL(k0_prep,   dim3(4),    dim3(256), 0, stream, cb, cnorm, cbh, flagcnt);
    hipLaunchKernelGGL(k1_mfma,   dim3(1024), dim3(256), 0, stream,
                       z, cbh, cnorm, out + IDX_OFF, flagcnt, flaglist);
    hipLaunchKernelGGL(k1b_refine, dim3(2048), dim3(256), 0, stream,
                       z, cb, cnorm, flagcnt, flaglist, out + IDX_OFF);
    hipLaunchKernelGGL(k2_scatter, dim3(4096), dim3(256), 0, stream,
                       z, cb, out + IDX_OFF, out, part);
    hipLaunchKernelGGL(k3_final,  dim3(1),    dim3(256), 0, stream, part, out);
}

// Round 4
// 260.173 us; speedup vs baseline: 7.7203x; 2.6880x over previous
//
#include <hip/hip_runtime.h>

#define HW 4096
#define NE 1024
#define LOSS_OFF 16777216
#define IDX_OFF  16777218
#define KP  264
#define KPB 528           // bytes per LDS tile row (256 fp16 + pad)
#define MARGIN 0.08f
#define RB 8              // refine rows per block

typedef __attribute__((ext_vector_type(8))) _Float16 half8v;
typedef __attribute__((ext_vector_type(4))) float float4v;

// ws layout (bytes): [0] int flag_count; [64..) int flaglist[65536];
// [262208..) float cnorm[1024]; [266304..) ushort cbh[1024*256]; [790592..) float part[4096]
#define WS_LIST_OFF   64
#define WS_CNORM_OFF  262208
#define WS_CBH_OFF    266304
#define WS_PART_OFF   790592

__device__ __forceinline__ unsigned short f16rne(float f) {
    _Float16 h = (_Float16)f;            // v_cvt_f16_f32, RNE
    return __builtin_bit_cast(unsigned short, h);
}

// ---------------- k0: codebook half-norms + fp16 conversion + counter zero ----------------
__global__ __launch_bounds__(256) void k0_prep(const float* __restrict__ cb,
                                               float* __restrict__ cnorm,
                                               unsigned short* __restrict__ cbh,
                                               int* __restrict__ flagcnt) {
    int e = blockIdx.x * 256 + threadIdx.x;   // grid 4 x 256 = 1024
    if (e == 0) *flagcnt = 0;
    const float4* row = (const float4*)(cb + (size_t)e * 256);
    unsigned short* dst = cbh + (size_t)e * 256;
    float s = 0.f;
#pragma unroll 8
    for (int i = 0; i < 64; ++i) {
        float4 v = row[i];
        s += v.x * v.x + v.y * v.y + v.z * v.z + v.w * v.w;
        unsigned p0 = (unsigned)f16rne(v.x) | ((unsigned)f16rne(v.y) << 16);
        unsigned p1 = (unsigned)f16rne(v.z) | ((unsigned)f16rne(v.w) << 16);
        *(uint2*)(dst + i * 4) = make_uint2(p0, p1);
    }
    cnorm[e] = 0.5f * s;
}

// ---------------- k1: fp16 MFMA approx distance + argmin(best1,best2) + flagging ----------------
__global__ __launch_bounds__(256, 2) void k1_mfma(const float* __restrict__ z,
                                                  const unsigned short* __restrict__ cbh,
                                                  const float* __restrict__ cnorm,
                                                  float* __restrict__ out_idx,
                                                  int* __restrict__ flagcnt,
                                                  int* __restrict__ flaglist) {
    __shared__ __align__(16) char smem[69632];
    char* zt = smem;                         // [64][KP] fp16 (aliases cb buf0; dead after A-read)
    char* cbbuf0 = smem;                     // [64][KP] fp16
    char* cbbuf1 = smem + 33792;
    float* cand1 = (float*)(smem + 67584);   // [64][2]
    int*   candi = (int*)  (smem + 68096);
    float* cand2 = (float*)(smem + 68608);

    const int tid = threadIdx.x;
    const int n0 = blockIdx.x * 64;
    const int hw0 = n0 & 4095;
    const float* zb = z + (size_t)(n0 >> 12) * (256 * HW);

    // ---- stage z tile transposed: [row][k] fp16 ----
    {
        const int row = tid & 63, kg8 = tid >> 6;
#pragma unroll
        for (int it = 0; it < 8; ++it) {
            int kb = (kg8 + it * 4) * 8;
            float v[8];
#pragma unroll
            for (int q = 0; q < 8; ++q) v[q] = zb[(size_t)(kb + q) * HW + hw0 + row];
            unsigned pk[4];
#pragma unroll
            for (int q = 0; q < 4; ++q)
                pk[q] = (unsigned)f16rne(v[2*q]) | ((unsigned)f16rne(v[2*q+1]) << 16);
            *(int4*)(zt + row * KPB + kb * 2) = make_int4(pk[0], pk[1], pk[2], pk[3]);
        }
    }
    __syncthreads();

    const int wid = tid >> 6, l = tid & 63;
    const int wy = wid >> 1, wx = wid & 1;
    const int lr = l & 15, lg = l >> 4;

    // ---- cache A-frags (this wave's 32 rows, full K) in registers ----
    half8v A[2][8];
#pragma unroll
    for (int mi = 0; mi < 2; ++mi)
#pragma unroll
        for (int ks = 0; ks < 8; ++ks)
            A[mi][ks] = *(const half8v*)(zt + (32*wy + 16*mi + lr) * KPB + (32*ks + 8*lg) * 2);
    __syncthreads();   // zt dead; cb buffers may now overwrite it

    // ---- stage codebook chunk 0 (64 entries x 256 k, fp16) ----
    const int se = tid >> 2;        // 0..63 entry
    const int sk0 = tid & 3;
#pragma unroll
    for (int it = 0; it < 8; ++it) {
        int kg = sk0 + it * 4;      // 0..31 (16B chunks)
        int4 v = *(const int4*)(cbh + (size_t)se * 256 + kg * 8);
        *(int4*)(cbbuf0 + se * KPB + kg * 16) = v;
    }
    __syncthreads();

    float b1[8], b2[8]; int bi[8];
#pragma unroll
    for (int i = 0; i < 8; ++i) { b1[i] = 1e30f; b2[i] = 1e30f; bi[i] = 0; }

    int buf = 0;
    for (int e0c = 0; e0c < 16; ++e0c) {
        // T14: issue next chunk's global loads early (into regs)
        int4 pf[8];
        if (e0c < 15) {
            const unsigned short* src = cbh + (size_t)(e0c + 1) * 64 * 256;
#pragma unroll
            for (int it = 0; it < 8; ++it) {
                int kg = sk0 + it * 4;
                pf[it] = *(const int4*)(src + (size_t)se * 256 + kg * 8);
            }
        }

        const char* cbp = buf ? cbbuf1 : cbbuf0;
        float4v acc00 = {0.f,0.f,0.f,0.f}, acc01 = acc00, acc10 = acc00, acc11 = acc00;
#pragma unroll
        for (int ks = 0; ks < 8; ++ks) {
            half8v B0 = *(const half8v*)(cbp + (32*wx + lr) * KPB + (32*ks + 8*lg) * 2);
            half8v B1 = *(const half8v*)(cbp + (32*wx + 16 + lr) * KPB + (32*ks + 8*lg) * 2);
            acc00 = __builtin_amdgcn_mfma_f32_16x16x32_f16(A[0][ks], B0, acc00, 0, 0, 0);
            acc01 = __builtin_amdgcn_mfma_f32_16x16x32_f16(A[0][ks], B1, acc01, 0, 0, 0);
            acc10 = __builtin_amdgcn_mfma_f32_16x16x32_f16(A[1][ks], B0, acc10, 0, 0, 0);
            acc11 = __builtin_amdgcn_mfma_f32_16x16x32_f16(A[1][ks], B1, acc11, 0, 0, 0);
        }

        // fold into best1/best2 (entries ascending -> strict < keeps smallest index)
        float cn0 = cnorm[e0c * 64 + 32 * wx + lr];
        float cn1 = cnorm[e0c * 64 + 32 * wx + 16 + lr];
        int e0v = e0c * 64 + 32 * wx + lr;
#pragma unroll
        for (int mi = 0; mi < 2; ++mi) {
            const float4v a0 = mi ? acc10 : acc00;
            const float4v a1 = mi ? acc11 : acc01;
#pragma unroll
            for (int r = 0; r < 4; ++r) {
                int slot = mi * 4 + r;
                float s0 = cn0 - a0[r];
                if (s0 < b1[slot]) { b2[slot] = b1[slot]; b1[slot] = s0; bi[slot] = e0v; }
                else if (s0 < b2[slot]) b2[slot] = s0;
                float s1 = cn1 - a1[r];
                if (s1 < b1[slot]) { b2[slot] = b1[slot]; b1[slot] = s1; bi[slot] = e0v + 16; }
                else if (s1 < b2[slot]) b2[slot] = s1;
            }
        }

        if (e0c < 15) {
            char* dst = buf ? cbbuf0 : cbbuf1;
#pragma unroll
            for (int it = 0; it < 8; ++it) {
                int kg = sk0 + it * 4;
                *(int4*)(dst + se * KPB + kg * 16) = pf[it];
            }
        }
        __syncthreads();
        buf ^= 1;
    }

    // ---- cross-lane argmin over the 16-lane entry dimension ----
#pragma unroll
    for (int m = 1; m <= 8; m <<= 1) {
#pragma unroll
        for (int s = 0; s < 8; ++s) {
            float o1 = __shfl_xor(b1[s], m, 64);
            float o2 = __shfl_xor(b2[s], m, 64);
            int   oi = __shfl_xor(bi[s], m, 64);
            float m2 = fminf(fmaxf(b1[s], o1), fminf(b2[s], o2));
            if (o1 < b1[s] || (o1 == b1[s] && oi < bi[s])) { b1[s] = o1; bi[s] = oi; }
            b2[s] = m2;
        }
    }
    if (lr == 0) {
#pragma unroll
        for (int mi = 0; mi < 2; ++mi)
#pragma unroll
            for (int r = 0; r < 4; ++r) {
                int row = 32 * wy + 16 * mi + 4 * lg + r;
                cand1[row * 2 + wx] = b1[mi * 4 + r];
                cand2[row * 2 + wx] = b2[mi * 4 + r];
                candi[row * 2 + wx] = bi[mi * 4 + r];
            }
    }
    __syncthreads();
    if (tid < 64) {
        float s1a = cand1[tid * 2], s1b = cand1[tid * 2 + 1];
        int   ia = candi[tid * 2],  ib = candi[tid * 2 + 1];
        float s2 = fminf(fminf(cand2[tid * 2], cand2[tid * 2 + 1]), fmaxf(s1a, s1b));
        float s1; int iw;
        if (s1b < s1a || (s1b == s1a && ib < ia)) { s1 = s1b; iw = ib; }
        else { s1 = s1a; iw = ia; }
        out_idx[n0 + tid] = (float)iw;
        if (s2 - s1 < MARGIN) {
            int p = atomicAdd(flagcnt, 1);
            flaglist[p] = n0 + tid;
        }
    }
}

// ---------------- k1b: exact fp32 re-argmin, 8 flagged rows per block ----------------
// zr reads are wave-broadcast (zero conflicts); codebook streamed ONCE per 8 rows.
// Same 4-way split-accumulator dot as the round-1-validated exact scan.
__global__ __launch_bounds__(256) void k1b_refine(const float* __restrict__ z,
                                                  const float* __restrict__ cb,
                                                  const float* __restrict__ cnorm,
                                                  const int* __restrict__ flagcnt,
                                                  const int* __restrict__ flaglist,
                                                  float* __restrict__ out_idx) {
    __shared__ float zr[RB][260];
    __shared__ int   rows[RB];
    __shared__ float wb[4][RB];
    __shared__ int   wi[4][RB];
    const int tid = threadIdx.x;
    const int lane = tid & 63, w = tid >> 6;
    const int count = *flagcnt;
    for (int base = blockIdx.x * RB; base < count; base += gridDim.x * RB) {
        const int nr = min(RB, count - base);
        __syncthreads();   // protect zr/rows/wb from previous iteration
        if (tid < nr) rows[tid] = flaglist[base + tid];
        __syncthreads();
        for (int r = 0; r < nr; ++r) {
            const int n = rows[r];
            zr[r][tid] = z[((size_t)(n >> 12) * 256 + tid) * HW + (n & 4095)];
        }
        __syncthreads();

        float best[RB]; int bidx[RB];
#pragma unroll
        for (int r = 0; r < RB; ++r) { best[r] = 1e30f; bidx[r] = 0; }

#pragma unroll
        for (int p = 0; p < 4; ++p) {
            const int e = p * 256 + tid;
            const float4* cv = (const float4*)(cb + (size_t)e * 256);
            float d0[RB], d1[RB], d2[RB], d3[RB];
#pragma unroll
            for (int r = 0; r < RB; ++r) { d0[r] = d1[r] = d2[r] = d3[r] = 0.f; }
#pragma unroll 8
            for (int q = 0; q < 64; ++q) {
                float4 c = cv[q];
#pragma unroll
                for (int r = 0; r < RB; ++r) {
                    float4 zv = *(const float4*)(&zr[r][q * 4]);   // broadcast
                    d0[r] = fmaf(zv.x, c.x, d0[r]);
                    d1[r] = fmaf(zv.y, c.y, d1[r]);
                    d2[r] = fmaf(zv.z, c.z, d2[r]);
                    d3[r] = fmaf(zv.w, c.w, d3[r]);
                }
            }
            const float cn = cnorm[e];
#pragma unroll
            for (int r = 0; r < RB; ++r) {
                float s = cn - ((d0[r] + d1[r]) + (d2[r] + d3[r]));
                if (s < best[r]) { best[r] = s; bidx[r] = e; }
            }
        }
        // cross-lane argmin (64 lanes), tie-break smaller index
#pragma unroll
        for (int m = 1; m <= 32; m <<= 1) {
#pragma unroll
            for (int r = 0; r < RB; ++r) {
                float ob = __shfl_xor(best[r], m, 64);
                int   oi = __shfl_xor(bidx[r], m, 64);
                if (ob < best[r] || (ob == best[r] && oi < bidx[r])) { best[r] = ob; bidx[r] = oi; }
            }
        }
        if (lane == 0) {
#pragma unroll
            for (int r = 0; r < RB; ++r) { wb[w][r] = best[r]; wi[w][r] = bidx[r]; }
        }
        __syncthreads();
        if (tid < nr) {
            float bb = wb[0][tid]; int ii = wi[0][tid];
#pragma unroll
            for (int q = 1; q < 4; ++q)
                if (wb[q][tid] < bb || (wb[q][tid] == bb && wi[q][tid] < ii)) { bb = wb[q][tid]; ii = wi[q][tid]; }
            out_idx[rows[tid]] = (float)ii;
        }
    }
}

// ---------------- k2: gather z_q + fused loss partials ----------------
__global__ __launch_bounds__(256) void k2_scatter(const float* __restrict__ z,
                                                  const float* __restrict__ cb,
                                                  const float* __restrict__ idxf,
                                                  float* __restrict__ zq,
                                                  float* __restrict__ part) {
    __shared__ float ls[4];
    size_t base = (size_t)blockIdx.x * 256 + threadIdx.x;   // grid 4096
    float lsum = 0.f;
#pragma unroll
    for (int it = 0; it < 16; ++it) {
        size_t flat = base + (size_t)it * 1048576;
        int c = (int)((flat >> 12) & 255);
        int n = (int)(((flat >> 20) << 12) | (flat & 4095));
        int e = (int)idxf[n];
        float q = cb[e * 256 + c];
        zq[flat] = q;
        float d = q - z[flat];
        lsum += d * d;
    }
#pragma unroll
    for (int m = 32; m >= 1; m >>= 1) lsum += __shfl_down(lsum, m, 64);
    int lane = threadIdx.x & 63, w = threadIdx.x >> 6;
    if (lane == 0) ls[w] = lsum;
    __syncthreads();
    if (threadIdx.x == 0) part[blockIdx.x] = ls[0] + ls[1] + ls[2] + ls[3];
}

// ---------------- k3: final loss reduce + constants ----------------
__global__ __launch_bounds__(256) void k3_final(const float* __restrict__ part,
                                                float* __restrict__ dout) {
    __shared__ float ls[4];
    float s = 0.f;
#pragma unroll
    for (int it = 0; it < 16; ++it) s += part[threadIdx.x + it * 256];
#pragma unroll
    for (int m = 32; m >= 1; m >>= 1) s += __shfl_down(s, m, 64);
    int lane = threadIdx.x & 63, w = threadIdx.x >> 6;
    if (lane == 0) ls[w] = s;
    __syncthreads();
    if (threadIdx.x == 0) {
        float total = ls[0] + ls[1] + ls[2] + ls[3];
        dout[LOSS_OFF]     = total / 16777216.0f;
        dout[LOSS_OFF + 1] = 0.0f;
    }
}

extern "C" void kernel_launch(void* const* d_in, const int* in_sizes, int n_in,
                              void* d_out, int out_size, void* d_ws, size_t ws_size,
                              hipStream_t stream) {
    const float* z  = (const float*)d_in[0];
    const float* cb = (const float*)d_in[1];
    float* out = (float*)d_out;
    char* ws = (char*)d_ws;

    int*            flagcnt  = (int*)ws;
    int*            flaglist = (int*)(ws + WS_LIST_OFF);
    float*          cnorm    = (float*)(ws + WS_CNORM_OFF);
    unsigned short* cbh      = (unsigned short*)(ws + WS_CBH_OFF);
    float*          part     = (float*)(ws + WS_PART_OFF);

    hipLaunchKernelGGL(k0_prep,   dim3(4),    dim3(256), 0, stream, cb, cnorm, cbh, flagcnt);
    hipLaunchKernelGGL(k1_mfma,   dim3(1024), dim3(256), 0, stream,
                       z, cbh, cnorm, out + IDX_OFF, flagcnt, flaglist);
    hipLaunchKernelGGL(k1b_refine, dim3(1024), dim3(256), 0, stream,
                       z, cb, cnorm, flagcnt, flaglist, out + IDX_OFF);
    hipLaunchKernelGGL(k2_scatter, dim3(4096), dim3(256), 0, stream,
                       z, cb, out + IDX_OFF, out, part);
    hipLaunchKernelGGL(k3_final,  dim3(1),    dim3(256), 0, stream, part, out);
}